// Round 6
// baseline (91.734 us; speedup 1.0000x reference)
//
#include <hip/hip_runtime.h>
#include <hip/hip_bf16.h>

typedef __attribute__((ext_vector_type(8))) __bf16 bf16x8;
typedef __attribute__((ext_vector_type(4))) float f32x4;

#define NROWS 16384
#define DIM   2048
#define NH1   512
#define NH2   32
#define MMEM  2048
#define BK    32
#define NT    (DIM / BK)   // 64 K-steps

// workspace byte offsets
#define W1O ((size_t)0)            // W1 bf16:  512*2048*2   = 2097152
#define W2O ((size_t)2097152)      // W2 bf16:  32*512*2     = 32768
#define AMO ((size_t)2129920)      // a_mem:    2048*32*2    = 131072
#define NMO ((size_t)2260992)      // n_mem:    2048*32*2    = 131072
#define HO  ((size_t)2392064)      // h bf16:   16384*512*2  = 16777216

__device__ __forceinline__ f32x4 mfma16(bf16x8 a, bf16x8 b, f32x4 c) {
    return __builtin_amdgcn_mfma_f32_16x16x32_bf16(a, b, c, 0, 0, 0);
}

__device__ __forceinline__ void gload_lds16(const void* g, void* l) {
    __builtin_amdgcn_global_load_lds(
        (const __attribute__((address_space(1))) void*)g,
        (__attribute__((address_space(3))) void*)l, 16, 0, 0);
}

__device__ __forceinline__ bf16x8 cvt8(f32x4 a, f32x4 b) {
    bf16x8 o;
    o[0] = (__bf16)a[0]; o[1] = (__bf16)a[1]; o[2] = (__bf16)a[2]; o[3] = (__bf16)a[3];
    o[4] = (__bf16)b[0]; o[5] = (__bf16)b[1]; o[6] = (__bf16)b[2]; o[7] = (__bf16)b[3];
    return o;
}

// ---------------- merged f32 -> bf16 conversion for W1, W2, am, nm ----------------
struct bf4 { __bf16 a, b, c, d; };

__global__ void cvt_all_kernel(const float* __restrict__ w1f, __bf16* __restrict__ w1b,
                               const float* __restrict__ w2f, __bf16* __restrict__ w2b,
                               const float* __restrict__ amf, __bf16* __restrict__ amb,
                               const float* __restrict__ nmf, __bf16* __restrict__ nmb) {
    const int g = blockIdx.x * blockDim.x + threadIdx.x;
    const int T = gridDim.x * blockDim.x;
    for (int i = g; i < (NH1 * DIM) / 4; i += T) {
        const float4 v = *reinterpret_cast<const float4*>(w1f + i * 4);
        *reinterpret_cast<bf4*>(w1b + i * 4) = { (__bf16)v.x, (__bf16)v.y, (__bf16)v.z, (__bf16)v.w };
    }
    for (int i = g; i < (NH2 * NH1) / 4; i += T) {
        const float4 v = *reinterpret_cast<const float4*>(w2f + i * 4);
        *reinterpret_cast<bf4*>(w2b + i * 4) = { (__bf16)v.x, (__bf16)v.y, (__bf16)v.z, (__bf16)v.w };
    }
    for (int i = g; i < (MMEM * NH2) / 4; i += T) {
        const float4 v = *reinterpret_cast<const float4*>(amf + i * 4);
        *reinterpret_cast<bf4*>(amb + i * 4) = { (__bf16)v.x, (__bf16)v.y, (__bf16)v.z, (__bf16)v.w };
    }
    for (int i = g; i < (MMEM * NH2) / 4; i += T) {
        const float4 v = *reinterpret_cast<const float4*>(nmf + i * 4);
        *reinterpret_cast<bf4*>(nmb + i * 4) = { (__bf16)v.x, (__bf16)v.y, (__bf16)v.z, (__bf16)v.w };
    }
}

// ---------------- GEMM1: h = relu(x @ W1^T + b1) ----------------
// 128x128 tile, BK=32, 4 waves (2x2, wave-tile 64x64).
// A (x, f32): 3-deep ring, global_load_lds, chunk^=(row&7) swizzle.
// B (W1, bf16): 4-deep ring, global_load_lds, chunk^=((row>>1)&3) swizzle
//   (bank-correct for 64B rows: (parity,slot) groups get exactly 2 lanes).
// Uniform loop: vmcnt(8) -> barrier -> issue stage(t+2)/(t+3) -> compute(t).
__global__ __launch_bounds__(256, 2) void gemm1_kernel(
    const float*  __restrict__ Xf,  // [NROWS][DIM] f32
    const __bf16* __restrict__ W1,  // [NH1][DIM] bf16
    const float*  __restrict__ b1,  // [NH1]
    __bf16* __restrict__ Hout)      // [NROWS][NH1]
{
    __shared__ float  As[3][128 * BK];   // 16KB each, 48KB
    __shared__ __bf16 Bs[4][128 * BK];   // 8KB each, 32KB
    const int tid  = threadIdx.x;
    const int lane = tid & 63;
    const int wave = tid >> 6;
    // XCD swizzle: nwg=512 = 8*64. XCD c gets orig c*64..c*64+63 (16 row-panels x 4 cols)
    const int b = blockIdx.x;
    const int orig = (b & 7) * 64 + (b >> 3);
    const int bn = orig & 3;    // 4 col tiles of 128
    const int bm = orig >> 2;   // 128 row tiles of 128
    const size_t brow = (size_t)bm * 128;
    const int bcol = bn * 128;
    const int wr = wave >> 1, wc = wave & 1;

    f32x4 acc[4][4];
#pragma unroll
    for (int m = 0; m < 4; ++m)
#pragma unroll
        for (int n = 0; n < 4; ++n) acc[m][n] = (f32x4){0.f, 0.f, 0.f, 0.f};

    // ---- A staging: 4 gloads/thread. row = q*32 + (tid>>3); stored slot = tid&7;
    // source chunk = (tid&7) ^ (row&7).
    const int aRowT = tid >> 3;                       // 0..31
    const int cA    = (tid & 7) ^ (aRowT & 7);        // 16B-chunk within 128B row
    const float* aSrcBase = Xf + (brow + aRowT) * (size_t)DIM + cA * 4;
    // ---- B staging: 2 gloads/thread. row = q*64 + (tid>>2); stored slot = tid&3;
    // source chunk = (tid&3) ^ ((row>>1)&3) = (tid&3)^((tid>>3)&3).
    const int bRowT = tid >> 2;                       // 0..63
    const int cB    = (tid & 3) ^ ((tid >> 3) & 3);   // 16B-chunk within 64B row
    const __bf16* bSrcBase = W1 + (size_t)(bcol + bRowT) * DIM + cB * 8;

#define STAGE_A(T, BI)                                                        \
    {                                                                         \
        const int k0_ = (T) * BK;                                             \
        _Pragma("unroll")                                                     \
        for (int q = 0; q < 4; ++q)                                           \
            gload_lds16(aSrcBase + (size_t)q * 32 * DIM + k0_,                \
                        (char*)As[BI] + q * 4096 + tid * 16);                 \
    }
#define STAGE_B(T, BI)                                                        \
    {                                                                         \
        const int k0_ = (T) * BK;                                             \
        _Pragma("unroll")                                                     \
        for (int q = 0; q < 2; ++q)                                           \
            gload_lds16(bSrcBase + (size_t)q * 64 * DIM + k0_,                \
                        (char*)Bs[BI] + q * 4096 + tid * 16);                 \
    }

    // ---- fragment read geometry (swizzled slots are loop-invariant)
    const int l15 = lane & 15;
    const int kc  = lane >> 4;
    const int l7  = lane & 7;
    const int rABase = wr * 64 + l15;    // (row&7)  == l7        for all m-frags
    const int rBBase = wc * 64 + l15;    // ((row>>1)&3) == (l15>>1)&3 for all n-frags
    const int aSlot0 = ((2 * kc)     ^ l7) << 4;
    const int aSlot1 = ((2 * kc + 1) ^ l7) << 4;
    const int bSlot  = (kc ^ ((l15 >> 1) & 3)) << 4;

#define COMPUTE(AI, BI)                                                       \
    {                                                                         \
        const char* Ac = (const char*)As[AI];                                 \
        const char* Bc = (const char*)Bs[BI];                                 \
        bf16x8 av[4], bv[4];                                                  \
        _Pragma("unroll")                                                     \
        for (int m = 0; m < 4; ++m) {                                         \
            const int rowB = (rABase + m * 16) * 128;                         \
            f32x4 lo = *(const f32x4*)(Ac + rowB + aSlot0);                   \
            f32x4 hi = *(const f32x4*)(Ac + rowB + aSlot1);                   \
            av[m] = cvt8(lo, hi);                                             \
        }                                                                     \
        _Pragma("unroll")                                                     \
        for (int n = 0; n < 4; ++n)                                           \
            bv[n] = *(const bf16x8*)(Bc + (rBBase + n * 16) * 64 + bSlot);    \
        __builtin_amdgcn_s_setprio(1);                                        \
        _Pragma("unroll")                                                     \
        for (int m = 0; m < 4; ++m)                                           \
            _Pragma("unroll")                                                 \
            for (int n = 0; n < 4; ++n)                                       \
                acc[m][n] = mfma16(av[m], bv[n], acc[m][n]);                  \
        __builtin_amdgcn_s_setprio(0);                                        \
    }

    // ===== prologue: A(0),B(0),A(1),B(1),B(2) -> 14 loads in flight =====
    STAGE_A(0, 0);
    STAGE_B(0, 0);
    STAGE_A(1, 1);
    STAGE_B(1, 1);
    STAGE_B(2, 2);

    // ===== uniform main loop =====
    // wait vmcnt(8): newest 8 = {B(t+1),A(t+1),B(t+2)} stay in flight;
    // A(t),B(t) and older are complete. Stages issued right after the
    // barrier (pre-compute): targets (t+2)%3 / (t+3)%4 were last read at
    // compute(t-1), finished before this barrier.
    int ia = 0;   // t % 3
    int i2 = 2;   // (t+2) % 3
    for (int t = 0; t < NT; ++t) {
        asm volatile("s_waitcnt vmcnt(8)" ::: "memory");
        __builtin_amdgcn_s_barrier();
        __builtin_amdgcn_sched_barrier(0);
        const int tA = (t + 2 < NT) ? (t + 2) : (NT - 1);
        const int tB = (t + 3 < NT) ? (t + 3) : (NT - 1);
        STAGE_A(tA, i2);
        STAGE_B(tB, (t + 3) & 3);
        __builtin_amdgcn_sched_barrier(0);
        COMPUTE(ia, t & 3);
        ia = (ia == 2) ? 0 : ia + 1;
        i2 = (i2 == 2) ? 0 : i2 + 1;
    }
#undef STAGE_A
#undef STAGE_B
#undef COMPUTE

    // epilogue: bias + relu + bf16 store. D layout: col=lane&15, row=(lane>>4)*4+reg
#pragma unroll
    for (int n = 0; n < 4; ++n) {
        const int gcol = bcol + wc * 64 + n * 16 + l15;
        const float bias = b1[gcol];
#pragma unroll
        for (int m = 0; m < 4; ++m) {
            const size_t grow0 = brow + wr * 64 + m * 16 + kc * 4;
#pragma unroll
            for (int r = 0; r < 4; ++r) {
                float v = acc[m][n][r] + bias;
                v = v > 0.f ? v : 0.f;
                Hout[(grow0 + r) * NH1 + gcol] = (__bf16)v;
            }
        }
    }
}

// ---------------- Tail: feat = h@W2^T + b2; scores; sigmoid ----------------
__global__ __launch_bounds__(512) void tail_kernel(
    const __bf16* __restrict__ Hin,  // [NROWS][NH1]
    const __bf16* __restrict__ W2b,  // [NH2][NH1]
    const float*  __restrict__ b2,   // [NH2]
    const __bf16* __restrict__ Am,   // [MMEM][NH2]
    const __bf16* __restrict__ Nm,   // [MMEM][NH2]
    float* __restrict__ out)         // [NROWS]
{
    __shared__ __bf16 featLds[64 * 32];
    __shared__ float aMaxLds[2][64];
    __shared__ float nMaxLds[2][64];
    const int tid  = threadIdx.x;
    const int lane = tid & 63;
    const int wave = tid >> 6;          // 0..7
    const int rowBase = blockIdx.x * 64;
    const int l15 = lane & 15;
    const int kc  = lane >> 4;
    const int rgrp  = (wave & 3) * 16;
    const int jHalf = wave >> 2;

    if (wave < 4) {
        f32x4 acc0 = {0.f,0.f,0.f,0.f}, acc1 = {0.f,0.f,0.f,0.f};
        const size_t hrow = (size_t)(rowBase + rgrp + l15) * NH1;
#pragma unroll
        for (int kk = 0; kk < 16; ++kk) {
            bf16x8 a  = *(const bf16x8*)(Hin + hrow + kk * 32 + kc * 8);
            bf16x8 w0 = *(const bf16x8*)(W2b + (size_t)l15 * NH1 + kk * 32 + kc * 8);
            bf16x8 w1 = *(const bf16x8*)(W2b + (size_t)(16 + l15) * NH1 + kk * 32 + kc * 8);
            acc0 = mfma16(a, w0, acc0);
            acc1 = mfma16(a, w1, acc1);
        }
        const float bias0 = b2[l15], bias1 = b2[16 + l15];
#pragma unroll
        for (int r = 0; r < 4; ++r) {
            const int lr = rgrp + kc * 4 + r;
            featLds[lr * 32 + l15]      = (__bf16)(acc0[r] + bias0);
            featLds[lr * 32 + 16 + l15] = (__bf16)(acc1[r] + bias1);
        }
    }
    __syncthreads();

    const bf16x8 af = *(const bf16x8*)&featLds[(rgrp + l15) * 32 + kc * 8];

    float rmaxA[4], rmaxN[4];
#pragma unroll
    for (int r = 0; r < 4; ++r) { rmaxA[r] = -1e30f; rmaxN[r] = -1e30f; }
    const f32x4 zero = {0.f,0.f,0.f,0.f};
    const int jBase = jHalf * (MMEM / 2);
#pragma unroll 2
    for (int jt = 0; jt < (MMEM / 2) / 16; jt += 4) {
        bf16x8 ba[4], bb[4];
#pragma unroll
        for (int u = 0; u < 4; ++u) {
            const size_t off = (size_t)(jBase + (jt + u) * 16 + l15) * NH2 + kc * 8;
            ba[u] = *(const bf16x8*)(Am + off);
            bb[u] = *(const bf16x8*)(Nm + off);
        }
#pragma unroll
        for (int u = 0; u < 4; ++u) {
            f32x4 sa = mfma16(af, ba[u], zero);
            f32x4 sn = mfma16(af, bb[u], zero);
#pragma unroll
            for (int r = 0; r < 4; ++r) {
                rmaxA[r] = fmaxf(rmaxA[r], sa[r]);
                rmaxN[r] = fmaxf(rmaxN[r], sn[r]);
            }
        }
    }
#pragma unroll
    for (int off = 1; off < 16; off <<= 1) {
#pragma unroll
        for (int r = 0; r < 4; ++r) {
            rmaxA[r] = fmaxf(rmaxA[r], __shfl_xor(rmaxA[r], off, 64));
            rmaxN[r] = fmaxf(rmaxN[r], __shfl_xor(rmaxN[r], off, 64));
        }
    }
    if (l15 == 0) {
#pragma unroll
        for (int r = 0; r < 4; ++r) {
            const int row = rgrp + kc * 4 + r;
            aMaxLds[jHalf][row] = rmaxA[r];
            nMaxLds[jHalf][row] = rmaxN[r];
        }
    }
    __syncthreads();
    if (tid < 64) {
        const float ma = fmaxf(aMaxLds[0][tid], aMaxLds[1][tid]);
        const float mn = fmaxf(nMaxLds[0][tid], nMaxLds[1][tid]);
        const float d = (ma - mn) * (1.0f / 32.0f);
        out[rowBase + tid] = 1.0f / (1.0f + __expf(-d));
    }
}

extern "C" void kernel_launch(void* const* d_in, const int* in_sizes, int n_in,
                              void* d_out, int out_size, void* d_ws, size_t ws_size,
                              hipStream_t stream) {
    (void)in_sizes; (void)n_in; (void)out_size; (void)ws_size;
    const float* x  = (const float*)d_in[0];
    const float* W1 = (const float*)d_in[1];
    const float* b1 = (const float*)d_in[2];
    const float* W2 = (const float*)d_in[3];
    const float* b2 = (const float*)d_in[4];
    const float* am = (const float*)d_in[5];
    const float* nm = (const float*)d_in[6];
    float* out = (float*)d_out;
    char* ws = (char*)d_ws;
    __bf16* w1b = (__bf16*)(ws + W1O);
    __bf16* w2b = (__bf16*)(ws + W2O);
    __bf16* amb = (__bf16*)(ws + AMO);
    __bf16* nmb = (__bf16*)(ws + NMO);
    __bf16* hb  = (__bf16*)(ws + HO);

    cvt_all_kernel<<<dim3(512), dim3(256), 0, stream>>>(W1, w1b, W2, w2b, am, amb, nm, nmb);
    gemm1_kernel<<<dim3((NROWS / 128) * (NH1 / 128)), dim3(256), 0, stream>>>(x, w1b, b1, hb);
    tail_kernel<<<dim3(NROWS / 64), dim3(512), 0, stream>>>(hb, w2b, b2, amb, nmb, out);
}

// Round 7
// 91.659 us; speedup vs baseline: 1.0008x; 1.0008x over previous
//
#include <hip/hip_runtime.h>
#include <hip/hip_bf16.h>

typedef __attribute__((ext_vector_type(8))) __bf16 bf16x8;
typedef __attribute__((ext_vector_type(4))) float f32x4;

#define NROWS 16384
#define DIM   2048
#define NH1   512
#define NH2   32
#define MMEM  2048
#define BK    32
#define NT    (DIM / BK)   // 64 K-steps

// workspace byte offsets
#define W1O ((size_t)0)            // W1 bf16:  512*2048*2   = 2097152
#define W2O ((size_t)2097152)      // W2 bf16:  32*512*2     = 32768
#define AMO ((size_t)2129920)      // a_mem:    2048*32*2    = 131072
#define NMO ((size_t)2260992)      // n_mem:    2048*32*2    = 131072
#define HO  ((size_t)2392064)      // h bf16:   16384*512*2  = 16777216

__device__ __forceinline__ f32x4 mfma16(bf16x8 a, bf16x8 b, f32x4 c) {
    return __builtin_amdgcn_mfma_f32_16x16x32_bf16(a, b, c, 0, 0, 0);
}

__device__ __forceinline__ void gload_lds16(const void* g, void* l) {
    __builtin_amdgcn_global_load_lds(
        (const __attribute__((address_space(1))) void*)g,
        (__attribute__((address_space(3))) void*)l, 16, 0, 0);
}

__device__ __forceinline__ bf16x8 cvt8(f32x4 a, f32x4 b) {
    bf16x8 o;
    o[0] = (__bf16)a[0]; o[1] = (__bf16)a[1]; o[2] = (__bf16)a[2]; o[3] = (__bf16)a[3];
    o[4] = (__bf16)b[0]; o[5] = (__bf16)b[1]; o[6] = (__bf16)b[2]; o[7] = (__bf16)b[3];
    return o;
}

// ---------------- merged f32 -> bf16 conversion for W1, W2, am, nm ----------------
struct bf4 { __bf16 a, b, c, d; };

__global__ void cvt_all_kernel(const float* __restrict__ w1f, __bf16* __restrict__ w1b,
                               const float* __restrict__ w2f, __bf16* __restrict__ w2b,
                               const float* __restrict__ amf, __bf16* __restrict__ amb,
                               const float* __restrict__ nmf, __bf16* __restrict__ nmb) {
    const int g = blockIdx.x * blockDim.x + threadIdx.x;
    const int T = gridDim.x * blockDim.x;
    for (int i = g; i < (NH1 * DIM) / 4; i += T) {
        const float4 v = *reinterpret_cast<const float4*>(w1f + i * 4);
        *reinterpret_cast<bf4*>(w1b + i * 4) = { (__bf16)v.x, (__bf16)v.y, (__bf16)v.z, (__bf16)v.w };
    }
    for (int i = g; i < (NH2 * NH1) / 4; i += T) {
        const float4 v = *reinterpret_cast<const float4*>(w2f + i * 4);
        *reinterpret_cast<bf4*>(w2b + i * 4) = { (__bf16)v.x, (__bf16)v.y, (__bf16)v.z, (__bf16)v.w };
    }
    for (int i = g; i < (MMEM * NH2) / 4; i += T) {
        const float4 v = *reinterpret_cast<const float4*>(amf + i * 4);
        *reinterpret_cast<bf4*>(amb + i * 4) = { (__bf16)v.x, (__bf16)v.y, (__bf16)v.z, (__bf16)v.w };
    }
    for (int i = g; i < (MMEM * NH2) / 4; i += T) {
        const float4 v = *reinterpret_cast<const float4*>(nmf + i * 4);
        *reinterpret_cast<bf4*>(nmb + i * 4) = { (__bf16)v.x, (__bf16)v.y, (__bf16)v.z, (__bf16)v.w };
    }
}

// ---------------- GEMM1: h = relu(x @ W1^T + b1) ----------------
// 64x128 tile, BK=32, 4 waves (2x2, wave-tile 32x64). Small LDS (32KB) for
// 4 blocks/CU occupancy; m97-style one-barrier-per-step double-buffered loop.
// Both operands via global_load_lds with pre-swizzled sources:
//   A (f32, 128B rows): slot ^= (row&7);  B (bf16, 64B rows): slot ^= ((row>>1)&3).
__global__ __launch_bounds__(256, 4) void gemm1_kernel(
    const float*  __restrict__ Xf,  // [NROWS][DIM] f32
    const __bf16* __restrict__ W1,  // [NH1][DIM] bf16
    const float*  __restrict__ b1,  // [NH1]
    __bf16* __restrict__ Hout)      // [NROWS][NH1]
{
    __shared__ float  Af[2][64 * BK];    // 8KB each
    __shared__ __bf16 Bs[2][128 * BK];   // 8KB each
    const int tid  = threadIdx.x;
    const int lane = tid & 63;
    const int wave = tid >> 6;
    // XCD swizzle: nwg=1024 = 8*128 (bijective). XCD c gets 128 consecutive orig.
    const int b = blockIdx.x;
    const int orig = (b & 7) * 128 + (b >> 3);
    const int bn = orig & 3;    // 4 col tiles of 128
    const int bm = orig >> 2;   // 256 row tiles of 64
    const size_t brow = (size_t)bm * 64;
    const int bcol = bn * 128;
    const int wr = wave >> 1, wc = wave & 1;

    f32x4 acc[2][4];
#pragma unroll
    for (int m = 0; m < 2; ++m)
#pragma unroll
        for (int n = 0; n < 4; ++n) acc[m][n] = (f32x4){0.f, 0.f, 0.f, 0.f};

    // ---- A staging: 2 gloads/thread. row = q*32 + (tid>>3); stored slot = tid&7;
    // source chunk = (tid&7) ^ (row&7) = (tid&7) ^ ((tid>>3)&7).
    const int aRowT = tid >> 3;                       // 0..31
    const int cA    = (tid & 7) ^ (aRowT & 7);        // 16B-chunk within 128B row
    const float* aSrcBase = Xf + (brow + aRowT) * (size_t)DIM + cA * 4;
    // ---- B staging: 2 gloads/thread. row = q*64 + (tid>>2); stored slot = tid&3;
    // source chunk = (tid&3) ^ ((row>>1)&3) = (tid&3) ^ ((tid>>3)&3).
    const int bRowT = tid >> 2;                       // 0..63
    const int cB    = (tid & 3) ^ ((tid >> 3) & 3);   // 16B-chunk within 64B row
    const __bf16* bSrcBase = W1 + (size_t)(bcol + bRowT) * DIM + cB * 8;

#define STAGE(T, BI)                                                          \
    {                                                                         \
        const int k0_ = (T) * BK;                                             \
        _Pragma("unroll")                                                     \
        for (int q = 0; q < 2; ++q)                                           \
            gload_lds16(aSrcBase + (size_t)q * 32 * DIM + k0_,                \
                        (char*)Af[BI] + q * 4096 + tid * 16);                 \
        _Pragma("unroll")                                                     \
        for (int q = 0; q < 2; ++q)                                           \
            gload_lds16(bSrcBase + (size_t)q * 64 * DIM + k0_,                \
                        (char*)Bs[BI] + q * 4096 + tid * 16);                 \
    }

    // ---- fragment read geometry (swizzled slots are loop-invariant)
    const int l15 = lane & 15;
    const int kc  = lane >> 4;
    const int l7  = lane & 7;
    const int rABase = wr * 32 + l15;    // (row&7) == l7 for both m-frags
    const int rBBase = wc * 64 + l15;    // ((row>>1)&3) == (l15>>1)&3 for all n-frags
    const int aSlot0 = ((2 * kc)     ^ l7) << 4;
    const int aSlot1 = ((2 * kc + 1) ^ l7) << 4;
    const int bSlot  = (kc ^ ((l15 >> 1) & 3)) << 4;

#define COMPUTE(BI)                                                           \
    {                                                                         \
        const char* Ac = (const char*)Af[BI];                                 \
        const char* Bc = (const char*)Bs[BI];                                 \
        bf16x8 av[2], bv[4];                                                  \
        _Pragma("unroll")                                                     \
        for (int m = 0; m < 2; ++m) {                                         \
            const int rowB = (rABase + m * 16) * 128;                         \
            f32x4 lo = *(const f32x4*)(Ac + rowB + aSlot0);                   \
            f32x4 hi = *(const f32x4*)(Ac + rowB + aSlot1);                   \
            av[m] = cvt8(lo, hi);                                             \
        }                                                                     \
        _Pragma("unroll")                                                     \
        for (int n = 0; n < 4; ++n)                                           \
            bv[n] = *(const bf16x8*)(Bc + (rBBase + n * 16) * 64 + bSlot);    \
        _Pragma("unroll")                                                     \
        for (int m = 0; m < 2; ++m)                                           \
            _Pragma("unroll")                                                 \
            for (int n = 0; n < 4; ++n)                                       \
                acc[m][n] = mfma16(av[m], bv[n], acc[m][n]);                  \
    }

    // ===== prologue =====
    STAGE(0, 0);
    __syncthreads();   // drains vmcnt(0): tile 0 resident

    // ===== main loop: stage(t+1) | compute(t) | sync =====
    for (int t = 0; t < NT; ++t) {
        if (t + 1 < NT) STAGE(t + 1, (t + 1) & 1);
        COMPUTE(t & 1);
        __syncthreads();  // implicit vmcnt(0)+lgkmcnt(0) drain; covered by 4 blocks/CU
    }
#undef STAGE
#undef COMPUTE

    // epilogue: bias + relu + bf16 store. D layout: col=lane&15, row=(lane>>4)*4+reg
#pragma unroll
    for (int n = 0; n < 4; ++n) {
        const int gcol = bcol + wc * 64 + n * 16 + l15;
        const float bias = b1[gcol];
#pragma unroll
        for (int m = 0; m < 2; ++m) {
            const size_t grow0 = brow + wr * 32 + m * 16 + kc * 4;
#pragma unroll
            for (int r = 0; r < 4; ++r) {
                float v = acc[m][n][r] + bias;
                v = v > 0.f ? v : 0.f;
                Hout[(grow0 + r) * NH1 + gcol] = (__bf16)v;
            }
        }
    }
}

// ---------------- Tail: feat = h@W2^T + b2; scores; sigmoid ----------------
__global__ __launch_bounds__(512) void tail_kernel(
    const __bf16* __restrict__ Hin,  // [NROWS][NH1]
    const __bf16* __restrict__ W2b,  // [NH2][NH1]
    const float*  __restrict__ b2,   // [NH2]
    const __bf16* __restrict__ Am,   // [MMEM][NH2]
    const __bf16* __restrict__ Nm,   // [MMEM][NH2]
    float* __restrict__ out)         // [NROWS]
{
    __shared__ __bf16 featLds[64 * 32];
    __shared__ float aMaxLds[2][64];
    __shared__ float nMaxLds[2][64];
    const int tid  = threadIdx.x;
    const int lane = tid & 63;
    const int wave = tid >> 6;          // 0..7
    const int rowBase = blockIdx.x * 64;
    const int l15 = lane & 15;
    const int kc  = lane >> 4;
    const int rgrp  = (wave & 3) * 16;
    const int jHalf = wave >> 2;

    if (wave < 4) {
        f32x4 acc0 = {0.f,0.f,0.f,0.f}, acc1 = {0.f,0.f,0.f,0.f};
        const size_t hrow = (size_t)(rowBase + rgrp + l15) * NH1;
#pragma unroll
        for (int kk = 0; kk < 16; ++kk) {
            bf16x8 a  = *(const bf16x8*)(Hin + hrow + kk * 32 + kc * 8);
            bf16x8 w0 = *(const bf16x8*)(W2b + (size_t)l15 * NH1 + kk * 32 + kc * 8);
            bf16x8 w1 = *(const bf16x8*)(W2b + (size_t)(16 + l15) * NH1 + kk * 32 + kc * 8);
            acc0 = mfma16(a, w0, acc0);
            acc1 = mfma16(a, w1, acc1);
        }
        const float bias0 = b2[l15], bias1 = b2[16 + l15];
#pragma unroll
        for (int r = 0; r < 4; ++r) {
            const int lr = rgrp + kc * 4 + r;
            featLds[lr * 32 + l15]      = (__bf16)(acc0[r] + bias0);
            featLds[lr * 32 + 16 + l15] = (__bf16)(acc1[r] + bias1);
        }
    }
    __syncthreads();

    const bf16x8 af = *(const bf16x8*)&featLds[(rgrp + l15) * 32 + kc * 8];

    float rmaxA[4], rmaxN[4];
#pragma unroll
    for (int r = 0; r < 4; ++r) { rmaxA[r] = -1e30f; rmaxN[r] = -1e30f; }
    const f32x4 zero = {0.f,0.f,0.f,0.f};
    const int jBase = jHalf * (MMEM / 2);
#pragma unroll 2
    for (int jt = 0; jt < (MMEM / 2) / 16; jt += 4) {
        bf16x8 ba[4], bb[4];
#pragma unroll
        for (int u = 0; u < 4; ++u) {
            const size_t off = (size_t)(jBase + (jt + u) * 16 + l15) * NH2 + kc * 8;
            ba[u] = *(const bf16x8*)(Am + off);
            bb[u] = *(const bf16x8*)(Nm + off);
        }
#pragma unroll
        for (int u = 0; u < 4; ++u) {
            f32x4 sa = mfma16(af, ba[u], zero);
            f32x4 sn = mfma16(af, bb[u], zero);
#pragma unroll
            for (int r = 0; r < 4; ++r) {
                rmaxA[r] = fmaxf(rmaxA[r], sa[r]);
                rmaxN[r] = fmaxf(rmaxN[r], sn[r]);
            }
        }
    }
#pragma unroll
    for (int off = 1; off < 16; off <<= 1) {
#pragma unroll
        for (int r = 0; r < 4; ++r) {
            rmaxA[r] = fmaxf(rmaxA[r], __shfl_xor(rmaxA[r], off, 64));
            rmaxN[r] = fmaxf(rmaxN[r], __shfl_xor(rmaxN[r], off, 64));
        }
    }
    if (l15 == 0) {
#pragma unroll
        for (int r = 0; r < 4; ++r) {
            const int row = rgrp + kc * 4 + r;
            aMaxLds[jHalf][row] = rmaxA[r];
            nMaxLds[jHalf][row] = rmaxN[r];
        }
    }
    __syncthreads();
    if (tid < 64) {
        const float ma = fmaxf(aMaxLds[0][tid], aMaxLds[1][tid]);
        const float mn = fmaxf(nMaxLds[0][tid], nMaxLds[1][tid]);
        const float d = (ma - mn) * (1.0f / 32.0f);
        out[rowBase + tid] = 1.0f / (1.0f + __expf(-d));
    }
}

extern "C" void kernel_launch(void* const* d_in, const int* in_sizes, int n_in,
                              void* d_out, int out_size, void* d_ws, size_t ws_size,
                              hipStream_t stream) {
    (void)in_sizes; (void)n_in; (void)out_size; (void)ws_size;
    const float* x  = (const float*)d_in[0];
    const float* W1 = (const float*)d_in[1];
    const float* b1 = (const float*)d_in[2];
    const float* W2 = (const float*)d_in[3];
    const float* b2 = (const float*)d_in[4];
    const float* am = (const float*)d_in[5];
    const float* nm = (const float*)d_in[6];
    float* out = (float*)d_out;
    char* ws = (char*)d_ws;
    __bf16* w1b = (__bf16*)(ws + W1O);
    __bf16* w2b = (__bf16*)(ws + W2O);
    __bf16* amb = (__bf16*)(ws + AMO);
    __bf16* nmb = (__bf16*)(ws + NMO);
    __bf16* hb  = (__bf16*)(ws + HO);

    cvt_all_kernel<<<dim3(512), dim3(256), 0, stream>>>(W1, w1b, W2, w2b, am, amb, nm, nmb);
    gemm1_kernel<<<dim3((NROWS / 64) * (NH1 / 128)), dim3(256), 0, stream>>>(x, w1b, b1, hb);
    tail_kernel<<<dim3(NROWS / 64), dim3(512), 0, stream>>>(hb, w2b, b2, amb, nmb, out);
}